// Round 8
// baseline (1179.706 us; speedup 1.0000x reference)
//
#include <hip/hip_runtime.h>
#include <math.h>

#define N_NODES 50000
#define N_EDGES 400000
#define CHUNK   100
#define NCH     2
#define OUTC    96
#define HID     192      // NCH*OUTC
#define HID2    384      // 2*HID
#define EPS     1e-5f

typedef __bf16 bf16x8 __attribute__((ext_vector_type(8)));
typedef float  f32x4  __attribute__((ext_vector_type(4)));

__device__ inline unsigned short f2bf(float f) {
    unsigned int u = __float_as_uint(f);
    unsigned int r = (u + 0x7FFFu + ((u >> 16) & 1u)) >> 16;   // RNE
    return (unsigned short)r;
}

// ---------------- prep: edge W1 [192][96] f32 -> bf16 W1^T [96][192] ----------------
#define W1T_SZ (96 * 192)
__global__ void prep_w1t(const float* __restrict__ W1, unsigned short* __restrict__ w1t)
{
    int i = blockIdx.x * 256 + threadIdx.x;
    if (i < W1T_SZ) {
        int j = i / HID, k = i % HID;
        w1t[i] = f2bf(W1[k * OUTC + j]);
    }
}

// ---------------- projection, f32 column-parallel (R7 verbatim — 50µs) ----------------
__global__ __launch_bounds__(192) void proj_kernel(
    const float* __restrict__ h, const float* __restrict__ W,
    const float* __restrict__ b, const float* __restrict__ g,
    const float* __restrict__ beta, float* __restrict__ hh)
{
    __shared__ float xs[16][NCH * CHUNK];   // 12.8 KB; reused as ys[16][192] after GEMM
    __shared__ float red[2][16][2][6];
    __shared__ float mv[2][16][2];
    const int tid = threadIdx.x;
    const int nbase = blockIdx.x * 16;

    for (int i = tid; i < 16 * 50; i += 192) {   // stage x as float4
        int row = i / 50, seg = i % 50;
        int n = nbase + row;
        float4 v = make_float4(0.f, 0.f, 0.f, 0.f);
        if (n < N_NODES) v = *(const float4*)&h[(size_t)n * (NCH * CHUNK) + seg * 4];
        *(float4*)&xs[row][seg * 4] = v;
    }
    __syncthreads();

    const int c = tid / OUTC, j = tid % OUTC;
    const float* wc = &W[c * CHUNK * OUTC];

    float acc[16];
    float bb = b[c * OUTC + j];
    #pragma unroll
    for (int i = 0; i < 16; ++i) acc[i] = bb;

    for (int d = 0; d < CHUNK; d += 4) {    // 25 steps
        float w0 = wc[(d + 0) * OUTC + j];
        float w1 = wc[(d + 1) * OUTC + j];
        float w2 = wc[(d + 2) * OUTC + j];
        float w3 = wc[(d + 3) * OUTC + j];
        #pragma unroll
        for (int i = 0; i < 16; ++i) {
            float4 hv = *(const float4*)&xs[i][c * CHUNK + d];
            acc[i] += hv.x * w0 + hv.y * w1 + hv.z * w2 + hv.w * w3;
        }
    }
    __syncthreads();
    float* ys = &xs[0][0];
    #pragma unroll
    for (int i = 0; i < 16; ++i) ys[i * HID + c * OUTC + j] = acc[i];
    __syncthreads();
    {
        int grp = tid / 6, q = tid % 6;       // 32 groups = 16 nodes x 2 chunks
        int gi = grp >> 1, gc = grp & 1;
        float s = 0.f, s2 = 0.f;
        #pragma unroll
        for (int t = 0; t < 16; ++t) {
            float v = ys[gi * HID + gc * OUTC + q + 6 * t];
            s += v; s2 += v * v;
        }
        red[0][gi][gc][q] = s; red[1][gi][gc][q] = s2;
    }
    __syncthreads();
    if (tid < 32) {
        int gi = tid >> 1, gc = tid & 1;
        float s = 0.f, s2 = 0.f;
        #pragma unroll
        for (int q = 0; q < 6; ++q) { s += red[0][gi][gc][q]; s2 += red[1][gi][gc][q]; }
        float mean = s * (1.f / 96.f);
        float var  = s2 * (1.f / 96.f) - mean * mean;
        mv[0][gi][gc] = mean;
        mv[1][gi][gc] = rsqrtf(var + EPS);
    }
    __syncthreads();
    float gg = g[c * OUTC + j], be = beta[c * OUTC + j];
    #pragma unroll
    for (int i = 0; i < 16; ++i) {
        int n = nbase + i;
        if (n < N_NODES) {
            float y = (acc[i] - mv[0][i][c]) * mv[1][i][c] * gg + be;
            y = (y < 0.f) ? 0.01f * y : y;
            hh[(size_t)n * HID + c * OUTC + j] = y;
        }
    }
}

// ---------------- CSR build (R7 verbatim) ----------------
__global__ void zero_deg_kernel(int* __restrict__ deg)
{
    int i = blockIdx.x * blockDim.x + threadIdx.x;
    if (i < N_NODES) deg[i] = 0;
}

__global__ void count_kernel(const int* __restrict__ dst, int* __restrict__ deg)
{
    int e = blockIdx.x * blockDim.x + threadIdx.x;
    if (e < N_EDGES) atomicAdd(&deg[dst[e]], 1);
}

__global__ __launch_bounds__(1024) void scan_kernel(
    const int* __restrict__ deg, int* __restrict__ rowstart,
    int* __restrict__ cursor, float* __restrict__ norm)
{
    __shared__ int sums[1024];
    const int t = threadIdx.x;
    const int L = (N_NODES + 1023) / 1024;   // 49
    int lo = t * L, hi = min(lo + L, N_NODES);
    int s = 0;
    for (int i = lo; i < hi; ++i) s += deg[i];
    sums[t] = s;
    __syncthreads();
    if (t == 0) {
        int run = 0;
        for (int i = 0; i < 1024; ++i) { int v = sums[i]; sums[i] = run; run += v; }
        rowstart[N_NODES] = run;
    }
    __syncthreads();
    int off = sums[t];
    for (int i = lo; i < hi; ++i) {
        int d = deg[i];
        rowstart[i] = off;
        cursor[i]   = off;
        norm[i]     = (d > 0) ? 1.f / (float)d : 0.f;
        off += d;
    }
}

// payload CSR: store edge id (for edge kernel) AND (src, dist) (for aggregate)
__global__ void fill_kernel(const int* __restrict__ src, const int* __restrict__ dst,
                            const float* __restrict__ dist, int* __restrict__ cursor,
                            int* __restrict__ eidx, int* __restrict__ csr_src,
                            float* __restrict__ csr_dist)
{
    int e = blockIdx.x * blockDim.x + threadIdx.x;
    if (e < N_EDGES) {
        int pos = atomicAdd(&cursor[dst[e]], 1);
        eidx[pos]     = e;
        csr_src[pos]  = src[e];
        csr_dist[pos] = dist[e];
    }
}

// ---------------- aggregation (R7 verbatim) ----------------
__global__ __launch_bounds__(256) void aggregate_kernel(
    const float* __restrict__ hh, const int* __restrict__ csr_src,
    const float* __restrict__ csr_dist, const int* __restrict__ rowstart,
    const float* __restrict__ norm, float* __restrict__ ahn)
{
    const int wave = threadIdx.x >> 6;
    const int lane = threadIdx.x & 63;
    const int v = blockIdx.x * 4 + wave;
    if (v >= N_NODES) return;
    const int r0 = rowstart[v], r1 = rowstart[v + 1];
    float a0 = 0.f, a1 = 0.f, a2 = 0.f;
    int k = r0;
    for (; k + 1 < r1; k += 2) {
        int   s0 = csr_src[k],      s1 = csr_src[k + 1];
        float d0 = csr_dist[k],     d1 = csr_dist[k + 1];
        const float* h0 = &hh[(size_t)s0 * HID];
        const float* h1 = &hh[(size_t)s1 * HID];
        a0 += h0[lane]       * d0 + h1[lane]       * d1;
        a1 += h0[lane + 64]  * d0 + h1[lane + 64]  * d1;
        a2 += h0[lane + 128] * d0 + h1[lane + 128] * d1;
    }
    if (k < r1) {
        int s0 = csr_src[k];
        float d0 = csr_dist[k];
        const float* h0 = &hh[(size_t)s0 * HID];
        a0 += h0[lane] * d0; a1 += h0[lane + 64] * d0; a2 += h0[lane + 128] * d0;
    }
    float nm = norm[v];
    ahn[(size_t)v * HID + lane]       = a0 * nm;
    ahn[(size_t)v * HID + lane + 64]  = a1 * nm;
    ahn[(size_t)v * HID + lane + 128] = a2 * nm;
}

// ---------------- GcnSAGE update v2: 1 wave/block, 3 cols/thread, 16 nodes ----------------
// LDS-read bound fix: re-read factor 3->1 (one wave per hc tile), 12 FMA per ds_read_b128.
// LN via 64-lane butterfly (no strided LDS reduce -> no bank conflicts).
__global__ __launch_bounds__(64) void update_kernel(
    float* __restrict__ hh, const float* __restrict__ ahn,
    const float* __restrict__ W, const float* __restrict__ b,
    const float* __restrict__ g, const float* __restrict__ beta)
{
    __shared__ float xs[16][HID2];   // 24.6 KB
    const int tid = threadIdx.x;     // 64 = 1 wave
    const int nbase = blockIdx.x * 16;

    for (int i = tid; i < 16 * 96; i += 64) {
        int row = i / 96, seg = i % 96;
        int n = nbase + row;
        float4 v = (seg < 48) ? *(const float4*)&hh[(size_t)n * HID + seg * 4]
                              : *(const float4*)&ahn[(size_t)n * HID + (seg - 48) * 4];
        *(float4*)&xs[row][seg * 4] = v;
    }
    __syncthreads();

    float acc[16][3];
    {
        float bb0 = b[tid], bb1 = b[tid + 64], bb2 = b[tid + 128];
        #pragma unroll
        for (int i = 0; i < 16; ++i) { acc[i][0] = bb0; acc[i][1] = bb1; acc[i][2] = bb2; }
    }

    #pragma unroll 2
    for (int d = 0; d < HID2; d += 4) {
        float wv[4][3];
        #pragma unroll
        for (int q = 0; q < 4; ++q) {
            const float* wr = &W[(size_t)(d + q) * HID + tid];
            wv[q][0] = wr[0]; wv[q][1] = wr[64]; wv[q][2] = wr[128];
        }
        #pragma unroll
        for (int i = 0; i < 16; ++i) {
            float4 hv = *(const float4*)&xs[i][d];   // wave-uniform: LDS broadcast
            #pragma unroll
            for (int c = 0; c < 3; ++c)
                acc[i][c] += hv.x * wv[0][c] + hv.y * wv[1][c] + hv.z * wv[2][c] + hv.w * wv[3][c];
        }
    }

    float gg0 = g[tid], gg1 = g[tid + 64], gg2 = g[tid + 128];
    float be0 = beta[tid], be1 = beta[tid + 64], be2 = beta[tid + 128];

    #pragma unroll
    for (int i = 0; i < 16; ++i) {
        float s  = acc[i][0] + acc[i][1] + acc[i][2];
        float s2 = acc[i][0] * acc[i][0] + acc[i][1] * acc[i][1] + acc[i][2] * acc[i][2];
        #pragma unroll
        for (int off = 1; off < 64; off <<= 1) {
            s  += __shfl_xor(s,  off, 64);
            s2 += __shfl_xor(s2, off, 64);
        }
        float mean = s * (1.f / HID);
        float var  = s2 * (1.f / HID) - mean * mean;
        float rstd = rsqrtf(var + EPS);
        float* hn = &hh[(size_t)(nbase + i) * HID + tid];
        float y0 = (acc[i][0] - mean) * rstd * gg0 + be0;
        float y1 = (acc[i][1] - mean) * rstd * gg1 + be1;
        float y2 = (acc[i][2] - mean) * rstd * gg2 + be2;
        hn[0]   = (y0 > 0.f) ? y0 : 0.f;
        hn[64]  = (y1 > 0.f) ? y1 : 0.f;
        hn[128] = (y2 > 0.f) ? y2 : 0.f;
    }
}

// ---------------- edge MLP via MFMA (R2 verbatim, bf16 — proven 3.9e-3) ----------------
__global__ __launch_bounds__(256) void edge_mfma_kernel(
    const float* __restrict__ hh, const int* __restrict__ src, const int* __restrict__ dst,
    const int* __restrict__ eidx,
    const unsigned short* __restrict__ w1t, const float* __restrict__ b1,
    const float* __restrict__ W2, const float* __restrict__ b2,
    float* __restrict__ out)
{
    __shared__ unsigned short he[64][200];   // 100 dw stride == 4 mod 32: conflict-free (R2)
    __shared__ int sidx[64], didx[64], eor[64];
    const int tid = threadIdx.x;
    const int ebase = blockIdx.x * 64;

    if (tid < 64) {
        int e = eidx[ebase + tid];
        eor[tid] = e;
        sidx[tid] = src[e];
        didx[tid] = dst[e];
    }
    __syncthreads();

    const int w    = tid >> 6;
    const int lane = tid & 63;
    const int lo   = lane & 15;
    const int hi   = lane >> 4;

    for (int i = 0; i < 16; ++i) {     // wave-private rows -> no 2nd barrier
        int slot = w * 16 + i;
        const float* hs = &hh[(size_t)sidx[slot] * HID];
        const float* hd = &hh[(size_t)didx[slot] * HID];
        float p0 = hs[lane]       * hd[lane];
        float p1 = hs[lane + 64]  * hd[lane + 64];
        float p2 = hs[lane + 128] * hd[lane + 128];
        he[slot][lane]       = f2bf(p0);
        he[slot][lane + 64]  = f2bf(p1);
        he[slot][lane + 128] = f2bf(p2);
    }

    f32x4 acc[6];
    #pragma unroll
    for (int nt = 0; nt < 6; ++nt) acc[nt] = (f32x4){0.f, 0.f, 0.f, 0.f};

    #pragma unroll
    for (int kt = 0; kt < 6; ++kt) {
        const int k0 = kt * 32 + hi * 8;
        bf16x8 af = *(const bf16x8*)&he[w * 16 + lo][k0];
        #pragma unroll
        for (int nt = 0; nt < 6; ++nt) {
            bf16x8 bfr = *(const bf16x8*)&w1t[(size_t)(nt * 16 + lo) * HID + k0];
            acc[nt] = __builtin_amdgcn_mfma_f32_16x16x32_bf16(af, bfr, acc[nt], 0, 0, 0);
        }
    }

    float b1c[6], w20[6], w21[6];
    #pragma unroll
    for (int nt = 0; nt < 6; ++nt) {
        int col = nt * 16 + lo;
        b1c[nt] = b1[col];
        w20[nt] = W2[col * 2 + 0];
        w21[nt] = W2[col * 2 + 1];
    }
    float bb0 = b2[0], bb1 = b2[1];
    #pragma unroll
    for (int reg = 0; reg < 4; ++reg) {
        float p0 = 0.f, p1 = 0.f;
        #pragma unroll
        for (int nt = 0; nt < 6; ++nt) {
            float hv = fmaxf(acc[nt][reg] + b1c[nt], 0.f);
            p0 += hv * w20[nt];
            p1 += hv * w21[nt];
        }
        #pragma unroll
        for (int off = 1; off < 16; off <<= 1) {
            p0 += __shfl_xor(p0, off, 64);
            p1 += __shfl_xor(p1, off, 64);
        }
        if (lo == 0) {
            int row = hi * 4 + reg;
            int e = eor[w * 16 + row];
            out[(size_t)e * 2 + 0] = p0 + bb0;
            out[(size_t)e * 2 + 1] = p1 + bb1;
        }
    }
}

// ---------------- launch ----------------
extern "C" void kernel_launch(void* const* d_in, const int* in_sizes, int n_in,
                              void* d_out, int out_size, void* d_ws, size_t ws_size,
                              hipStream_t stream)
{
    const float* h         = (const float*)d_in[0];
    const float* dist      = (const float*)d_in[1];
    const int*   src       = (const int*)  d_in[2];
    const int*   dst       = (const int*)  d_in[3];
    const float* proj_W    = (const float*)d_in[4];
    const float* proj_b    = (const float*)d_in[5];
    const float* proj_g    = (const float*)d_in[6];
    const float* proj_beta = (const float*)d_in[7];
    const float* gcn_W     = (const float*)d_in[8];
    const float* gcn_b     = (const float*)d_in[9];
    const float* gcn_g     = (const float*)d_in[10];
    const float* gcn_beta  = (const float*)d_in[11];
    const float* ep_W1     = (const float*)d_in[12];
    const float* ep_b1     = (const float*)d_in[13];
    const float* ep_W2     = (const float*)d_in[14];
    const float* ep_b2     = (const float*)d_in[15];
    float* out = (float*)d_out;

    char* p = (char*)d_ws;
    float* hh  = (float*)p;  p += (size_t)N_NODES * HID * sizeof(float);
    float* ahn = (float*)p;  p += (size_t)N_NODES * HID * sizeof(float);
    float* nrm = (float*)p;  p += (size_t)N_NODES * sizeof(float);
    int* deg      = (int*)p; p += (size_t)N_NODES * sizeof(int);
    int* rowstart = (int*)p; p += (size_t)(N_NODES + 1) * sizeof(int);
    int* cursor   = (int*)p; p += (size_t)N_NODES * sizeof(int);
    int* eidx     = (int*)p; p += (size_t)N_EDGES * sizeof(int);
    int* csr_src  = (int*)p; p += (size_t)N_EDGES * sizeof(int);
    float* csr_dist = (float*)p; p += (size_t)N_EDGES * sizeof(float);
    p = (char*)(((uintptr_t)p + 255) & ~(uintptr_t)255);
    unsigned short* w1t = (unsigned short*)p; p += (size_t)W1T_SZ * sizeof(unsigned short);

    // prep + projection (f32 column-parallel)
    prep_w1t<<<(W1T_SZ + 255) / 256, 256, 0, stream>>>(ep_W1, w1t);
    proj_kernel<<<(N_NODES + 15) / 16, 192, 0, stream>>>(
        h, proj_W, proj_b, proj_g, proj_beta, hh);
    // CSR build (payload)
    zero_deg_kernel<<<(N_NODES + 255) / 256, 256, 0, stream>>>(deg);
    count_kernel<<<(N_EDGES + 255) / 256, 256, 0, stream>>>(dst, deg);
    scan_kernel<<<1, 1024, 0, stream>>>(deg, rowstart, cursor, nrm);
    fill_kernel<<<(N_EDGES + 255) / 256, 256, 0, stream>>>(
        src, dst, dist, cursor, eidx, csr_src, csr_dist);
    // 2 GcnSAGE layers (update v2: 1-wave blocks, 3 cols/thread)
    for (int l = 0; l < 2; ++l) {
        aggregate_kernel<<<(N_NODES + 3) / 4, 256, 0, stream>>>(
            hh, csr_src, csr_dist, rowstart, nrm, ahn);
        update_kernel<<<N_NODES / 16, 64, 0, stream>>>(
            hh, ahn, gcn_W + (size_t)l * HID2 * HID, gcn_b + l * HID,
            gcn_g + l * HID, gcn_beta + l * HID);
    }
    // edge MLP (MFMA, bf16 — R2 verbatim)
    edge_mfma_kernel<<<N_EDGES / 64, 256, 0, stream>>>(
        hh, src, dst, eidx, w1t, ep_b1, ep_W2, ep_b2, out);
}

// Round 9
// 730.550 us; speedup vs baseline: 1.6148x; 1.6148x over previous
//
#include <hip/hip_runtime.h>
#include <math.h>

#define N_NODES 50000
#define N_EDGES 400000
#define CHUNK   100
#define NCH     2
#define OUTC    96
#define HID     192      // NCH*OUTC
#define HID2    384      // 2*HID
#define EPS     1e-5f

typedef __bf16 bf16x8 __attribute__((ext_vector_type(8)));
typedef float  f32x4  __attribute__((ext_vector_type(4)));

__device__ inline unsigned short f2bf(float f) {
    unsigned int u = __float_as_uint(f);
    unsigned int r = (u + 0x7FFFu + ((u >> 16) & 1u)) >> 16;   // RNE
    return (unsigned short)r;
}

// ---------------- prep: edge W1 [192][96] f32 -> bf16 W1^T [96][192] ----------------
#define W1T_SZ (96 * 192)
__global__ void prep_w1t(const float* __restrict__ W1, unsigned short* __restrict__ w1t)
{
    int i = blockIdx.x * 256 + threadIdx.x;
    if (i < W1T_SZ) {
        int j = i / HID, k = i % HID;
        w1t[i] = f2bf(W1[k * OUTC + j]);
    }
}

// ---------------- projection, f32 column-parallel (R7 verbatim — ~50µs) ----------------
__global__ __launch_bounds__(192) void proj_kernel(
    const float* __restrict__ h, const float* __restrict__ W,
    const float* __restrict__ b, const float* __restrict__ g,
    const float* __restrict__ beta, float* __restrict__ hh)
{
    __shared__ float xs[16][NCH * CHUNK];   // 12.8 KB; reused as ys[16][192] after GEMM
    __shared__ float red[2][16][2][6];
    __shared__ float mv[2][16][2];
    const int tid = threadIdx.x;
    const int nbase = blockIdx.x * 16;

    for (int i = tid; i < 16 * 50; i += 192) {   // stage x as float4
        int row = i / 50, seg = i % 50;
        int n = nbase + row;
        float4 v = make_float4(0.f, 0.f, 0.f, 0.f);
        if (n < N_NODES) v = *(const float4*)&h[(size_t)n * (NCH * CHUNK) + seg * 4];
        *(float4*)&xs[row][seg * 4] = v;
    }
    __syncthreads();

    const int c = tid / OUTC, j = tid % OUTC;
    const float* wc = &W[c * CHUNK * OUTC];

    float acc[16];
    float bb = b[c * OUTC + j];
    #pragma unroll
    for (int i = 0; i < 16; ++i) acc[i] = bb;

    for (int d = 0; d < CHUNK; d += 4) {    // 25 steps
        float w0 = wc[(d + 0) * OUTC + j];
        float w1 = wc[(d + 1) * OUTC + j];
        float w2 = wc[(d + 2) * OUTC + j];
        float w3 = wc[(d + 3) * OUTC + j];
        #pragma unroll
        for (int i = 0; i < 16; ++i) {
            float4 hv = *(const float4*)&xs[i][c * CHUNK + d];
            acc[i] += hv.x * w0 + hv.y * w1 + hv.z * w2 + hv.w * w3;
        }
    }
    __syncthreads();
    float* ys = &xs[0][0];
    #pragma unroll
    for (int i = 0; i < 16; ++i) ys[i * HID + c * OUTC + j] = acc[i];
    __syncthreads();
    {
        int grp = tid / 6, q = tid % 6;       // 32 groups = 16 nodes x 2 chunks
        int gi = grp >> 1, gc = grp & 1;
        float s = 0.f, s2 = 0.f;
        #pragma unroll
        for (int t = 0; t < 16; ++t) {
            float v = ys[gi * HID + gc * OUTC + q + 6 * t];
            s += v; s2 += v * v;
        }
        red[0][gi][gc][q] = s; red[1][gi][gc][q] = s2;
    }
    __syncthreads();
    if (tid < 32) {
        int gi = tid >> 1, gc = tid & 1;
        float s = 0.f, s2 = 0.f;
        #pragma unroll
        for (int q = 0; q < 6; ++q) { s += red[0][gi][gc][q]; s2 += red[1][gi][gc][q]; }
        float mean = s * (1.f / 96.f);
        float var  = s2 * (1.f / 96.f) - mean * mean;
        mv[0][gi][gc] = mean;
        mv[1][gi][gc] = rsqrtf(var + EPS);
    }
    __syncthreads();
    float gg = g[c * OUTC + j], be = beta[c * OUTC + j];
    #pragma unroll
    for (int i = 0; i < 16; ++i) {
        int n = nbase + i;
        if (n < N_NODES) {
            float y = (acc[i] - mv[0][i][c]) * mv[1][i][c] * gg + be;
            y = (y < 0.f) ? 0.01f * y : y;
            hh[(size_t)n * HID + c * OUTC + j] = y;
        }
    }
}

// ---------------- CSR build (R7 verbatim) ----------------
__global__ void zero_deg_kernel(int* __restrict__ deg)
{
    int i = blockIdx.x * blockDim.x + threadIdx.x;
    if (i < N_NODES) deg[i] = 0;
}

__global__ void count_kernel(const int* __restrict__ dst, int* __restrict__ deg)
{
    int e = blockIdx.x * blockDim.x + threadIdx.x;
    if (e < N_EDGES) atomicAdd(&deg[dst[e]], 1);
}

__global__ __launch_bounds__(1024) void scan_kernel(
    const int* __restrict__ deg, int* __restrict__ rowstart,
    int* __restrict__ cursor, float* __restrict__ norm)
{
    __shared__ int sums[1024];
    const int t = threadIdx.x;
    const int L = (N_NODES + 1023) / 1024;   // 49
    int lo = t * L, hi = min(lo + L, N_NODES);
    int s = 0;
    for (int i = lo; i < hi; ++i) s += deg[i];
    sums[t] = s;
    __syncthreads();
    if (t == 0) {
        int run = 0;
        for (int i = 0; i < 1024; ++i) { int v = sums[i]; sums[i] = run; run += v; }
        rowstart[N_NODES] = run;
    }
    __syncthreads();
    int off = sums[t];
    for (int i = lo; i < hi; ++i) {
        int d = deg[i];
        rowstart[i] = off;
        cursor[i]   = off;
        norm[i]     = (d > 0) ? 1.f / (float)d : 0.f;
        off += d;
    }
}

// payload CSR: store edge id (for edge kernel) AND (src, dist) (for aggregate)
__global__ void fill_kernel(const int* __restrict__ src, const int* __restrict__ dst,
                            const float* __restrict__ dist, int* __restrict__ cursor,
                            int* __restrict__ eidx, int* __restrict__ csr_src,
                            float* __restrict__ csr_dist)
{
    int e = blockIdx.x * blockDim.x + threadIdx.x;
    if (e < N_EDGES) {
        int pos = atomicAdd(&cursor[dst[e]], 1);
        eidx[pos]     = e;
        csr_src[pos]  = src[e];
        csr_dist[pos] = dist[e];
    }
}

// ---------------- aggregation (R7 verbatim) ----------------
__global__ __launch_bounds__(256) void aggregate_kernel(
    const float* __restrict__ hh, const int* __restrict__ csr_src,
    const float* __restrict__ csr_dist, const int* __restrict__ rowstart,
    const float* __restrict__ norm, float* __restrict__ ahn)
{
    const int wave = threadIdx.x >> 6;
    const int lane = threadIdx.x & 63;
    const int v = blockIdx.x * 4 + wave;
    if (v >= N_NODES) return;
    const int r0 = rowstart[v], r1 = rowstart[v + 1];
    float a0 = 0.f, a1 = 0.f, a2 = 0.f;
    int k = r0;
    for (; k + 1 < r1; k += 2) {
        int   s0 = csr_src[k],      s1 = csr_src[k + 1];
        float d0 = csr_dist[k],     d1 = csr_dist[k + 1];
        const float* h0 = &hh[(size_t)s0 * HID];
        const float* h1 = &hh[(size_t)s1 * HID];
        a0 += h0[lane]       * d0 + h1[lane]       * d1;
        a1 += h0[lane + 64]  * d0 + h1[lane + 64]  * d1;
        a2 += h0[lane + 128] * d0 + h1[lane + 128] * d1;
    }
    if (k < r1) {
        int s0 = csr_src[k];
        float d0 = csr_dist[k];
        const float* h0 = &hh[(size_t)s0 * HID];
        a0 += h0[lane] * d0; a1 += h0[lane + 64] * d0; a2 += h0[lane + 128] * d0;
    }
    float nm = norm[v];
    ahn[(size_t)v * HID + lane]       = a0 * nm;
    ahn[(size_t)v * HID + lane + 64]  = a1 * nm;
    ahn[(size_t)v * HID + lane + 128] = a2 * nm;
}

// ---------------- GcnSAGE update v3: thread = node, W via wave-uniform s_load ----------------
// 256 thr = 4 waves, 64 nodes/block; wave w owns cols [48w, 48w+48). No LDS GEMM staging:
// x = per-lane float4 VMEM from the node's own row; W[k][j0..j0+48) wave-uniform -> SGPR,
// 48 independent v_fmac per k (deep ILP hides latency; VALU issue ~all FMA).
// The LN __syncthreads also orders all row-reads before the in-place row-writes.
__global__ __launch_bounds__(256) void update_kernel(
    float* __restrict__ hh, const float* __restrict__ ahn,
    const float* __restrict__ W, const float* __restrict__ b,
    const float* __restrict__ g, const float* __restrict__ beta)
{
    __shared__ float red[64][4][2];   // 2 KB: per-node LN partials from each wave
    const int tid  = threadIdx.x;
    const int lane = tid & 63;
    const int j0   = __builtin_amdgcn_readfirstlane((tid >> 6) * 48);  // force SGPR
    const int wv   = j0 / 48;
    const int node = blockIdx.x * 64 + lane;
    const bool valid = (node < N_NODES);
    const int nclamp = valid ? node : (N_NODES - 1);

    float acc[48];
    #pragma unroll
    for (int j = 0; j < 48; ++j) acc[j] = b[j0 + j];

    const float* __restrict__ xrow = &hh[(size_t)nclamp * HID];
    const float* __restrict__ arow = &ahn[(size_t)nclamp * HID];

    // k in [0,192): x from hh
    for (int k4 = 0; k4 < HID; k4 += 4) {
        float4 xv = *(const float4*)&xrow[k4];
        const float xq[4] = { xv.x, xv.y, xv.z, xv.w };
        #pragma unroll
        for (int q = 0; q < 4; ++q) {
            const float* __restrict__ wr = &W[(size_t)(k4 + q) * HID + j0];
            #pragma unroll
            for (int j = 0; j < 48; ++j) acc[j] += xq[q] * wr[j];
        }
    }
    // k in [192,384): x from ahn (already degree-normalized by aggregate)
    for (int k4 = 0; k4 < HID; k4 += 4) {
        float4 xv = *(const float4*)&arow[k4];
        const float xq[4] = { xv.x, xv.y, xv.z, xv.w };
        #pragma unroll
        for (int q = 0; q < 4; ++q) {
            const float* __restrict__ wr = &W[(size_t)(HID + k4 + q) * HID + j0];
            #pragma unroll
            for (int j = 0; j < 48; ++j) acc[j] += xq[q] * wr[j];
        }
    }

    // LN partials (48 cols per wave) -> LDS exchange across the 4 waves
    float s = 0.f, s2 = 0.f;
    #pragma unroll
    for (int j = 0; j < 48; ++j) { s += acc[j]; s2 += acc[j] * acc[j]; }
    red[lane][wv][0] = s;
    red[lane][wv][1] = s2;
    __syncthreads();    // also: all hh-row reads complete before any write below
    float st = 0.f, s2t = 0.f;
    #pragma unroll
    for (int w2 = 0; w2 < 4; ++w2) { st += red[lane][w2][0]; s2t += red[lane][w2][1]; }
    float mean = st * (1.f / HID);
    float var  = s2t * (1.f / HID) - mean * mean;
    float rstd = rsqrtf(var + EPS);

    if (valid) {
        float* orow = &hh[(size_t)node * HID + j0];
        #pragma unroll
        for (int jv = 0; jv < 12; ++jv) {
            float4 o;
            float y0 = (acc[jv*4+0] - mean) * rstd * g[j0+jv*4+0] + beta[j0+jv*4+0];
            float y1 = (acc[jv*4+1] - mean) * rstd * g[j0+jv*4+1] + beta[j0+jv*4+1];
            float y2 = (acc[jv*4+2] - mean) * rstd * g[j0+jv*4+2] + beta[j0+jv*4+2];
            float y3 = (acc[jv*4+3] - mean) * rstd * g[j0+jv*4+3] + beta[j0+jv*4+3];
            o.x = fmaxf(y0, 0.f); o.y = fmaxf(y1, 0.f);
            o.z = fmaxf(y2, 0.f); o.w = fmaxf(y3, 0.f);
            *(float4*)&orow[jv * 4] = o;
        }
    }
}

// ---------------- edge MLP via MFMA (R2 verbatim, bf16 — proven 3.9e-3) ----------------
__global__ __launch_bounds__(256) void edge_mfma_kernel(
    const float* __restrict__ hh, const int* __restrict__ src, const int* __restrict__ dst,
    const int* __restrict__ eidx,
    const unsigned short* __restrict__ w1t, const float* __restrict__ b1,
    const float* __restrict__ W2, const float* __restrict__ b2,
    float* __restrict__ out)
{
    __shared__ unsigned short he[64][200];   // 100 dw stride == 4 mod 32: conflict-free (R2)
    __shared__ int sidx[64], didx[64], eor[64];
    const int tid = threadIdx.x;
    const int ebase = blockIdx.x * 64;

    if (tid < 64) {
        int e = eidx[ebase + tid];
        eor[tid] = e;
        sidx[tid] = src[e];
        didx[tid] = dst[e];
    }
    __syncthreads();

    const int w    = tid >> 6;
    const int lane = tid & 63;
    const int lo   = lane & 15;
    const int hi   = lane >> 4;

    for (int i = 0; i < 16; ++i) {     // wave-private rows -> no 2nd barrier
        int slot = w * 16 + i;
        const float* hs = &hh[(size_t)sidx[slot] * HID];
        const float* hd = &hh[(size_t)didx[slot] * HID];
        float p0 = hs[lane]       * hd[lane];
        float p1 = hs[lane + 64]  * hd[lane + 64];
        float p2 = hs[lane + 128] * hd[lane + 128];
        he[slot][lane]       = f2bf(p0);
        he[slot][lane + 64]  = f2bf(p1);
        he[slot][lane + 128] = f2bf(p2);
    }

    f32x4 acc[6];
    #pragma unroll
    for (int nt = 0; nt < 6; ++nt) acc[nt] = (f32x4){0.f, 0.f, 0.f, 0.f};

    #pragma unroll
    for (int kt = 0; kt < 6; ++kt) {
        const int k0 = kt * 32 + hi * 8;
        bf16x8 af = *(const bf16x8*)&he[w * 16 + lo][k0];
        #pragma unroll
        for (int nt = 0; nt < 6; ++nt) {
            bf16x8 bfr = *(const bf16x8*)&w1t[(size_t)(nt * 16 + lo) * HID + k0];
            acc[nt] = __builtin_amdgcn_mfma_f32_16x16x32_bf16(af, bfr, acc[nt], 0, 0, 0);
        }
    }

    float b1c[6], w20[6], w21[6];
    #pragma unroll
    for (int nt = 0; nt < 6; ++nt) {
        int col = nt * 16 + lo;
        b1c[nt] = b1[col];
        w20[nt] = W2[col * 2 + 0];
        w21[nt] = W2[col * 2 + 1];
    }
    float bb0 = b2[0], bb1 = b2[1];
    #pragma unroll
    for (int reg = 0; reg < 4; ++reg) {
        float p0 = 0.f, p1 = 0.f;
        #pragma unroll
        for (int nt = 0; nt < 6; ++nt) {
            float hv = fmaxf(acc[nt][reg] + b1c[nt], 0.f);
            p0 += hv * w20[nt];
            p1 += hv * w21[nt];
        }
        #pragma unroll
        for (int off = 1; off < 16; off <<= 1) {
            p0 += __shfl_xor(p0, off, 64);
            p1 += __shfl_xor(p1, off, 64);
        }
        if (lo == 0) {
            int row = hi * 4 + reg;
            int e = eor[w * 16 + row];
            out[(size_t)e * 2 + 0] = p0 + bb0;
            out[(size_t)e * 2 + 1] = p1 + bb1;
        }
    }
}

// ---------------- launch ----------------
extern "C" void kernel_launch(void* const* d_in, const int* in_sizes, int n_in,
                              void* d_out, int out_size, void* d_ws, size_t ws_size,
                              hipStream_t stream)
{
    const float* h         = (const float*)d_in[0];
    const float* dist      = (const float*)d_in[1];
    const int*   src       = (const int*)  d_in[2];
    const int*   dst       = (const int*)  d_in[3];
    const float* proj_W    = (const float*)d_in[4];
    const float* proj_b    = (const float*)d_in[5];
    const float* proj_g    = (const float*)d_in[6];
    const float* proj_beta = (const float*)d_in[7];
    const float* gcn_W     = (const float*)d_in[8];
    const float* gcn_b     = (const float*)d_in[9];
    const float* gcn_g     = (const float*)d_in[10];
    const float* gcn_beta  = (const float*)d_in[11];
    const float* ep_W1     = (const float*)d_in[12];
    const float* ep_b1     = (const float*)d_in[13];
    const float* ep_W2     = (const float*)d_in[14];
    const float* ep_b2     = (const float*)d_in[15];
    float* out = (float*)d_out;

    char* p = (char*)d_ws;
    float* hh  = (float*)p;  p += (size_t)N_NODES * HID * sizeof(float);
    float* ahn = (float*)p;  p += (size_t)N_NODES * HID * sizeof(float);
    float* nrm = (float*)p;  p += (size_t)N_NODES * sizeof(float);
    int* deg      = (int*)p; p += (size_t)N_NODES * sizeof(int);
    int* rowstart = (int*)p; p += (size_t)(N_NODES + 1) * sizeof(int);
    int* cursor   = (int*)p; p += (size_t)N_NODES * sizeof(int);
    int* eidx     = (int*)p; p += (size_t)N_EDGES * sizeof(int);
    int* csr_src  = (int*)p; p += (size_t)N_EDGES * sizeof(int);
    float* csr_dist = (float*)p; p += (size_t)N_EDGES * sizeof(float);
    p = (char*)(((uintptr_t)p + 255) & ~(uintptr_t)255);
    unsigned short* w1t = (unsigned short*)p; p += (size_t)W1T_SZ * sizeof(unsigned short);

    // prep + projection (f32 column-parallel)
    prep_w1t<<<(W1T_SZ + 255) / 256, 256, 0, stream>>>(ep_W1, w1t);
    proj_kernel<<<(N_NODES + 15) / 16, 192, 0, stream>>>(
        h, proj_W, proj_b, proj_g, proj_beta, hh);
    // CSR build (payload)
    zero_deg_kernel<<<(N_NODES + 255) / 256, 256, 0, stream>>>(deg);
    count_kernel<<<(N_EDGES + 255) / 256, 256, 0, stream>>>(dst, deg);
    scan_kernel<<<1, 1024, 0, stream>>>(deg, rowstart, cursor, nrm);
    fill_kernel<<<(N_EDGES + 255) / 256, 256, 0, stream>>>(
        src, dst, dist, cursor, eidx, csr_src, csr_dist);
    // 2 GcnSAGE layers (update v3: thread=node, SGPR-streamed W)
    for (int l = 0; l < 2; ++l) {
        aggregate_kernel<<<(N_NODES + 3) / 4, 256, 0, stream>>>(
            hh, csr_src, csr_dist, rowstart, nrm, ahn);
        update_kernel<<<(N_NODES + 63) / 64, 256, 0, stream>>>(
            hh, ahn, gcn_W + (size_t)l * HID2 * HID, gcn_b + l * HID,
            gcn_g + l * HID, gcn_beta + l * HID);
    }
    // edge MLP (MFMA, bf16 — R2 verbatim)
    edge_mfma_kernel<<<N_EDGES / 64, 256, 0, stream>>>(
        hh, src, dst, eidx, w1t, ep_b1, ep_W2, ep_b2, out);
}